// Round 11
// baseline (1318.690 us; speedup 1.0000x reference)
//
#include <hip/hip_runtime.h>
#include <hip/hip_bf16.h>
#include <stdint.h>

// Problem constants (from reference)
#define B_      8
#define N_      16384
#define NPOINT  512
#define KNN_    16
#define C_      16

// Exact IEEE f32 ops — bit-match the numpy (ref=np) lowering:
//   p2/s2 : np.sum(v*v,-1)  -> pairwise small-n ASCENDING:  (x2+y2)+z2, no FMA
//   FPS d : np.sum(dd*dd,-1)-> ASCENDING:  (dx2+dy2)+dz2, no FMA
//   dot   : np.einsum unopt -> sum_of_products_contig_two remainder switch,
//           DESCENDING fallthrough:  ((sz*pz) + sy*py) + sx*px, no FMA
//   dist  : (s2 + p2) - 2*dot   elementwise, no FMA
__device__ __forceinline__ float fmulrn(float a, float b){ return __fmul_rn(a,b); }
__device__ __forceinline__ float faddrn(float a, float b){ return __fadd_rn(a,b); }
__device__ __forceinline__ float fsubrn(float a, float b){ return __fsub_rn(a,b); }

// ---------------------------------------------------------------------------
// Kernel 1: pack {x, y, z, p2} per point.  p2 = (x*x + y*y) + z*z  (ascending).
// ---------------------------------------------------------------------------
__global__ void prep_kernel(const float* __restrict__ x, float4* __restrict__ pts){
    int i = blockIdx.x * blockDim.x + threadIdx.x;   // 0 .. B_*N_-1
    if (i >= B_ * N_) return;
    const float4* x4 = (const float4*)x;             // x row = 16 floats = 4 float4
    float4 q = x4[(size_t)i * 4];                    // channels 0..3: x,y,z,c3
    float p2 = faddrn(faddrn(fmulrn(q.x,q.x), fmulrn(q.y,q.y)), fmulrn(q.z,q.z));
    pts[i] = make_float4(q.x, q.y, q.z, p2);
}

// ---------------------------------------------------------------------------
// Kernel 2: furthest point sampling, one block per batch.
// R5-R10 post-mortem: the allocator will NOT keep 48 coord values live
// (VGPR pinned at ~52 across scalars/pins/waves_per_eu; reloads or spills
// every iteration = the 1000-1450us plateau). New structure makes low VGPR
// correct BY DESIGN: (x,y) planes live in 128KiB dynamic LDS (re-read each
// iteration at 128B/cyc, overlapped with VALU); only z (16 named scalars)
// and md (16 named scalars, loop-carried => guaranteed resident) in regs.
// Working set ~47 VGPR == the allocator's comfort zone.
// Reduce: u64 key {hi = f32 bits of min_d, lo = ~idx} -> single 64-bit max
// == (max value, min index) == numpy first-occurrence argmax.
// ---------------------------------------------------------------------------
#define FPS_T   1024
#define FPS_NW  (FPS_T/64)     // 16 waves
#define FPS_LDS_BYTES (N_ * 2 * (int)sizeof(float))   // 131072 = 128 KiB

#define FOR_SLOTS(F) F(0) F(1) F(2) F(3) F(4) F(5) F(6) F(7) \
                     F(8) F(9) F(10) F(11) F(12) F(13) F(14) F(15)

__global__ void __launch_bounds__(FPS_T)
__attribute__((amdgpu_waves_per_eu(4, 4)))
fps_kernel(const float4* __restrict__ pts, float4* __restrict__ s_out){
    extern __shared__ float2 xy[];                 // [N_] staged (x,y) pairs
    __shared__ unsigned long long red[2][FPS_NW];

    const int b    = blockIdx.x;
    const int tid  = threadIdx.x;
    const int lane = tid & 63;
    const int wv   = tid >> 6;
    const float4* P = pts + (size_t)b * N_;

    // z + md as 32 named scalars — md is loop-carried (must stay in regs);
    // z may be kept or re-read from L1, either overlaps with VALU.
#define DECL_SLOT(s) float z##s, md##s;
    FOR_SLOTS(DECL_SLOT)
#undef DECL_SLOT

    // Stage (x,y) into LDS; keep z in scalars.
#define INIT_SLOT(s) { float4 q = P[(s) * FPS_T + tid]; \
        xy[(s) * FPS_T + tid] = make_float2(q.x, q.y); \
        z##s = q.z; md##s = 1e10f; }
    FOR_SLOTS(INIT_SLOT)
#undef INIT_SLOT

    float lx, ly, lz;
    {
        float4 q0 = P[0];                    // seed = index 0
        lx = q0.x; ly = q0.y; lz = q0.z;
        if (tid == 0) s_out[(size_t)b * NPOINT + 0] = q0;
    }
    __syncthreads();                         // staging visible to all

    for (int it = 1; it < NPOINT; ++it){
        float    bv = -1.0f;                 // all min_d >= 0
        uint32_t bi = 0;
        // slots ascend in global index -> strict > keeps first occurrence
#define DO_SLOT(s) { \
        float2 c = xy[(s) * FPS_T + tid]; \
        float dx = fsubrn(c.x, lx); \
        float dy = fsubrn(c.y, ly); \
        float dz = fsubrn(z##s, lz); \
        float d  = faddrn(faddrn(fmulrn(dx,dx), fmulrn(dy,dy)), fmulrn(dz,dz)); \
        md##s = fminf(md##s, d); \
        if (md##s > bv){ bv = md##s; bi = (uint32_t)((s) * FPS_T + tid); } }
        FOR_SLOTS(DO_SLOT)
#undef DO_SLOT

        // u64 key: (max value, min index) via single 64-bit max
        unsigned long long k =
            ((unsigned long long)__float_as_uint(bv) << 32) |
            (unsigned long long)(~bi);
        #pragma unroll
        for (int off = 1; off < 64; off <<= 1){
            unsigned long long o = __shfl_xor(k, off, 64);
            if (o > k) k = o;
        }
        const int par = it & 1;
        if (lane == 0) red[par][wv] = k;
        __syncthreads();
        // lane-parallel scan: entry (lane&15), replicated 4x; xor-max is safe
        unsigned long long g = red[par][lane & 15];
        #pragma unroll
        for (int off = 1; off < 64; off <<= 1){
            unsigned long long o = __shfl_xor(g, off, 64);
            if (o > g) g = o;
        }
        uint32_t gi  = ~((uint32_t)g);       // lo field was ~idx
        uint32_t giu = (uint32_t)__builtin_amdgcn_readfirstlane((int)gi);
        float4 q = P[giu];                   // block-uniform scalar load
        lx = q.x; ly = q.y; lz = q.z;
        if (tid == 0) s_out[(size_t)b * NPOINT + it] = q;
    }
}

// ---------------------------------------------------------------------------
// Kernel 3: exact 16-NN per sample row (one wave per row, 4 rows per block).
//   dot  = ((sz*pz) + sy*py) + sx*px   [np.einsum contig_two DESCENDING tail]
//   dist = (s2 + p2) - 2*dot
// Total order = (monotone u32 key, idx) packed u64 in 16 NAMED u64 scalars.
// R10 lesson: unroll-1 exposed ~200cyc L2 latency per iteration -> manual
// 4-way unroll issues 4 independent dwordx4 loads per group (4x MLP).
// ---------------------------------------------------------------------------
#define FOR_V(F) F(0) F(1) F(2) F(3) F(4) F(5) F(6) F(7) \
                 F(8) F(9) F(10) F(11) F(12) F(13) F(14) F(15)

__global__ void __launch_bounds__(256)
__attribute__((amdgpu_waves_per_eu(4, 4)))
knn_kernel(const float* __restrict__ x,
           const float4* __restrict__ pts,
           const float4* __restrict__ s_arr,
           float* __restrict__ out){
    const int wv   = threadIdx.x >> 6;
    const int lane = threadIdx.x & 63;
    const int blk  = blockIdx.x;            // 0 .. B_*NPOINT/4 - 1
    const int b    = blk >> 7;              // 128 blocks per batch
    const int p    = ((blk & 127) << 2) | wv;

    const float4 s = s_arr[(size_t)b * NPOINT + p];
    const float sx = s.x, sy = s.y, sz = s.z, s2 = s.w;
    const float4* P = pts + (size_t)b * N_;

#define DECLV(t) unsigned long long v##t = ~0ULL;
    FOR_V(DECLV)
#undef DECLV

#define PROC(q, n) { \
        float dot = faddrn(faddrn(fmulrn(sz, (q).z), fmulrn(sy, (q).y)), fmulrn(sx, (q).x)); \
        float d = fsubrn(faddrn(s2, (q).w), fmulrn(2.0f, dot)); \
        uint32_t bits = __float_as_uint(d); \
        uint32_t key  = bits ^ (((uint32_t)((int32_t)bits >> 31)) | 0x80000000u); \
        unsigned long long c = ((unsigned long long)key << 32) | (uint32_t)(n); \
        if (c < v15){ \
            INS(0) INS(1) INS(2) INS(3) INS(4) INS(5) INS(6) INS(7) \
            INS(8) INS(9) INS(10) INS(11) INS(12) INS(13) INS(14) INS(15) \
        } }
#define INS(t) { bool lt = c < v##t; \
                 unsigned long long lo = lt ? c : v##t; \
                 unsigned long long hi = lt ? v##t : c; \
                 v##t = lo; c = hi; }

    #pragma unroll 1
    for (int j = 0; j < N_/64; j += 4){
        const int n0 = (j << 6) | lane;
        float4 q0 = P[n0];
        float4 q1 = P[n0 + 64];
        float4 q2 = P[n0 + 128];
        float4 q3 = P[n0 + 192];
        PROC(q0, n0)
        PROC(q1, n0 + 64)
        PROC(q2, n0 + 128)
        PROC(q3, n0 + 192)
    }
#undef INS
#undef PROC

    // merge: 16 rounds of wave-min over per-lane heads; winner lane consumes.
    uint32_t myidx = 0;
    const int myr = lane >> 2;
    #pragma unroll 1
    for (int r = 0; r < KNN_; ++r){
        unsigned long long h = v0;
        unsigned long long g = h;
        #pragma unroll
        for (int off = 1; off < 64; off <<= 1){
            unsigned long long o = __shfl_xor(g, off, 64);
            if (o < g) g = o;
        }
        if (h == g){                          // unique winner (idx is unique)
            v0=v1; v1=v2; v2=v3; v3=v4; v4=v5; v5=v6; v6=v7; v7=v8;
            v8=v9; v9=v10; v10=v11; v11=v12; v12=v13; v13=v14; v14=v15;
            v15=~0ULL;
        }
        if (myr == r) myidx = (uint32_t)g;    // keep idx of my output row
    }

    // gather + write: lane l handles neighbor r=l>>2, channels 4*(l&3)..+3
    const int c4 = lane & 3;
    const float4* X4 = (const float4*)x;
    float4 valq = X4[((size_t)b * N_ + myidx) * 4 + c4];
    float4* O4 = (float4*)out;
    O4[(((size_t)b * NPOINT + p) * KNN_ + myr) * 4 + c4] = valq;
}

// ---------------------------------------------------------------------------
extern "C" void kernel_launch(void* const* d_in, const int* in_sizes, int n_in,
                              void* d_out, int out_size, void* d_ws, size_t ws_size,
                              hipStream_t stream) {
    const float* x = (const float*)d_in[0];
    float* out = (float*)d_out;

    // workspace layout: [B_*N_ float4 packed points][B_*NPOINT float4 samples]
    const size_t pts_bytes = (size_t)B_ * N_ * sizeof(float4);
    const size_t s_bytes   = (size_t)B_ * NPOINT * sizeof(float4);
    if (ws_size < pts_bytes + s_bytes) return;   // visible failure if ws too small
    float4* pts   = (float4*)d_ws;
    float4* s_arr = (float4*)((char*)d_ws + pts_bytes);

    prep_kernel<<<(B_*N_ + 255)/256, 256, 0, stream>>>(x, pts);
    fps_kernel<<<B_, FPS_T, FPS_LDS_BYTES, stream>>>(pts, s_arr);
    knn_kernel<<<(B_*NPOINT)/4, 256, 0, stream>>>(x, pts, s_arr, out);
}

// Round 12
// 1115.916 us; speedup vs baseline: 1.1817x; 1.1817x over previous
//
#include <hip/hip_runtime.h>
#include <hip/hip_bf16.h>
#include <stdint.h>

// Problem constants (from reference)
#define B_      8
#define N_      16384
#define NPOINT  512
#define KNN_    16
#define C_      16

// Exact IEEE f32 ops — bit-match the numpy (ref=np) lowering:
//   p2/s2 : np.sum(v*v,-1)  -> pairwise small-n ASCENDING:  (x2+y2)+z2, no FMA
//   FPS d : np.sum(dd*dd,-1)-> ASCENDING:  (dx2+dy2)+dz2, no FMA
//   dot   : np.einsum unopt -> sum_of_products_contig_two remainder switch,
//           DESCENDING fallthrough:  ((sz*pz) + sy*py) + sx*px, no FMA
//   dist  : (s2 + p2) - 2*dot   elementwise, no FMA
__device__ __forceinline__ float fmulrn(float a, float b){ return __fmul_rn(a,b); }
__device__ __forceinline__ float faddrn(float a, float b){ return __fadd_rn(a,b); }
__device__ __forceinline__ float fsubrn(float a, float b){ return __fsub_rn(a,b); }

// ---------------------------------------------------------------------------
// DPP-based reductions (VALU pipe, zero LDS ops, no lgkmcnt waits).
// row_shr:n ctrl = 0x110|n. old = x everywhere -> invalid/masked lanes keep x
// (op(x,x) = x, identity-safe for max).
// ---------------------------------------------------------------------------
__device__ __forceinline__ uint32_t umax_(uint32_t a, uint32_t b){ return a > b ? a : b; }

// 4-step row reduce: lane 15 of each 16-lane row = max of that row.
__device__ __forceinline__ uint32_t row16_max(uint32_t x){
    uint32_t t;
    t = (uint32_t)__builtin_amdgcn_update_dpp((int)x, (int)x, 0x111, 0xf, 0xf, false); x = umax_(x, t);
    t = (uint32_t)__builtin_amdgcn_update_dpp((int)x, (int)x, 0x112, 0xf, 0xf, false); x = umax_(x, t);
    t = (uint32_t)__builtin_amdgcn_update_dpp((int)x, (int)x, 0x114, 0xf, 0xf, false); x = umax_(x, t);
    t = (uint32_t)__builtin_amdgcn_update_dpp((int)x, (int)x, 0x118, 0xf, 0xf, false); x = umax_(x, t);
    return x;
}

// Full 64-lane max as a UNIFORM value: row reduce + 4 readlane + scalar max.
__device__ __forceinline__ uint32_t wave_max_uniform(uint32_t x){
    x = row16_max(x);
    uint32_t a = (uint32_t)__builtin_amdgcn_readlane((int)x, 15);
    uint32_t b = (uint32_t)__builtin_amdgcn_readlane((int)x, 31);
    uint32_t c = (uint32_t)__builtin_amdgcn_readlane((int)x, 47);
    uint32_t d = (uint32_t)__builtin_amdgcn_readlane((int)x, 63);
    return umax_(umax_(a, b), umax_(c, d));
}

// ---------------------------------------------------------------------------
// Kernel 1: pack {x, y, z, p2} per point.  p2 = (x*x + y*y) + z*z  (ascending).
// ---------------------------------------------------------------------------
__global__ void prep_kernel(const float* __restrict__ x, float4* __restrict__ pts){
    int i = blockIdx.x * blockDim.x + threadIdx.x;   // 0 .. B_*N_-1
    if (i >= B_ * N_) return;
    const float4* x4 = (const float4*)x;             // x row = 16 floats = 4 float4
    float4 q = x4[(size_t)i * 4];                    // channels 0..3: x,y,z,c3
    float p2 = faddrn(faddrn(fmulrn(q.x,q.x), fmulrn(q.y,q.y)), fmulrn(q.z,q.z));
    pts[i] = make_float4(q.x, q.y, q.z, p2);
}

// ---------------------------------------------------------------------------
// Kernel 2: furthest point sampling, one block per batch.
// R10/R11 post-mortem: the bottleneck was the REDUCE path — 24 dependent u64
// shfl_xor = 48 ds_bpermute per iter (~2200 cyc LDS pipe) + lgkm waits; the
// coord source (regs vs LDS) was irrelevant. This round: DPP row_shr max +
// readlane + s_max (VALU/SALU, ZERO LDS ops). Value = f32 bits of min_d
// (monotone u32, >=0); index tie-break via masked max of ~bi (== min idx,
// 0 identity). First-occurrence argmax preserved exactly at every level.
// Coords: (x,y) in 128KiB dynamic LDS, z + md as 32 named scalar registers.
// ---------------------------------------------------------------------------
#define FPS_T   1024
#define FPS_NW  (FPS_T/64)     // 16 waves
#define FPS_LDS_BYTES (N_ * 2 * (int)sizeof(float))   // 131072 = 128 KiB

#define FOR_SLOTS(F) F(0) F(1) F(2) F(3) F(4) F(5) F(6) F(7) \
                     F(8) F(9) F(10) F(11) F(12) F(13) F(14) F(15)

__global__ void __launch_bounds__(FPS_T)
__attribute__((amdgpu_waves_per_eu(4, 4)))
fps_kernel(const float4* __restrict__ pts, float4* __restrict__ s_out){
    extern __shared__ float2 xy[];                 // [N_] staged (x,y) pairs
    __shared__ uint32_t red_v[2][FPS_NW];
    __shared__ uint32_t red_i[2][FPS_NW];

    const int b    = blockIdx.x;
    const int tid  = threadIdx.x;
    const int lane = tid & 63;
    const int wv   = tid >> 6;
    const float4* P = pts + (size_t)b * N_;

#define DECL_SLOT(s) float z##s, md##s;
    FOR_SLOTS(DECL_SLOT)
#undef DECL_SLOT

#define INIT_SLOT(s) { float4 q = P[(s) * FPS_T + tid]; \
        xy[(s) * FPS_T + tid] = make_float2(q.x, q.y); \
        z##s = q.z; md##s = 1e10f; }
    FOR_SLOTS(INIT_SLOT)
#undef INIT_SLOT

    float lx, ly, lz;
    {
        float4 q0 = P[0];                    // seed = index 0
        lx = q0.x; ly = q0.y; lz = q0.z;
        if (tid == 0) s_out[(size_t)b * NPOINT + 0] = q0;
    }
    __syncthreads();                         // staging visible to all

    for (int it = 1; it < NPOINT; ++it){
        float    bv = -1.0f;                 // all min_d >= 0
        uint32_t bi = 0;
        // slots ascend in global index -> strict > keeps first occurrence
#define DO_SLOT(s) { \
        float2 c = xy[(s) * FPS_T + tid]; \
        float dx = fsubrn(c.x, lx); \
        float dy = fsubrn(c.y, ly); \
        float dz = fsubrn(z##s, lz); \
        float d  = faddrn(faddrn(fmulrn(dx,dx), fmulrn(dy,dy)), fmulrn(dz,dz)); \
        md##s = fminf(md##s, d); \
        if (md##s > bv){ bv = md##s; bi = (uint32_t)((s) * FPS_T + tid); } }
        FOR_SLOTS(DO_SLOT)
#undef DO_SLOT

        // ---- wave reduce (DPP, uniform results) ----
        uint32_t vb    = __float_as_uint(bv);          // monotone key (>=0)
        uint32_t gmaxw = wave_max_uniform(vb);
        uint32_t gidxw = wave_max_uniform((vb == gmaxw) ? ~bi : 0u); // = ~min_bi
        const int par = it & 1;
        if (lane == 0){ red_v[par][wv] = gmaxw; red_i[par][wv] = gidxw; }
        __syncthreads();
        // ---- block reduce: 16 entries, same-address broadcast reads ----
        uint32_t rv = red_v[par][lane & 15];
        uint32_t ri = red_i[par][lane & 15];
        uint32_t gv = (uint32_t)__builtin_amdgcn_readlane((int)row16_max(rv), 15);
        uint32_t gn = (uint32_t)__builtin_amdgcn_readlane(
                          (int)row16_max((rv == gv) ? ri : 0u), 15);
        uint32_t gi = ~gn;                   // global (max val, min idx) winner
        float4 q = P[gi];                    // uniform index -> scalar load path
        lx = q.x; ly = q.y; lz = q.z;
        if (tid == 0) s_out[(size_t)b * NPOINT + it] = q;
    }
}

// ---------------------------------------------------------------------------
// Kernel 3: exact 16-NN per sample row (one wave per row, 4 rows per block).
// UNCHANGED from R11 (byte-identical) to isolate the fps delta; its ~280us
// anomaly is next round's target with subtraction evidence.
// ---------------------------------------------------------------------------
#define FOR_V(F) F(0) F(1) F(2) F(3) F(4) F(5) F(6) F(7) \
                 F(8) F(9) F(10) F(11) F(12) F(13) F(14) F(15)

__global__ void __launch_bounds__(256)
__attribute__((amdgpu_waves_per_eu(4, 4)))
knn_kernel(const float* __restrict__ x,
           const float4* __restrict__ pts,
           const float4* __restrict__ s_arr,
           float* __restrict__ out){
    const int wv   = threadIdx.x >> 6;
    const int lane = threadIdx.x & 63;
    const int blk  = blockIdx.x;            // 0 .. B_*NPOINT/4 - 1
    const int b    = blk >> 7;              // 128 blocks per batch
    const int p    = ((blk & 127) << 2) | wv;

    const float4 s = s_arr[(size_t)b * NPOINT + p];
    const float sx = s.x, sy = s.y, sz = s.z, s2 = s.w;
    const float4* P = pts + (size_t)b * N_;

#define DECLV(t) unsigned long long v##t = ~0ULL;
    FOR_V(DECLV)
#undef DECLV

#define PROC(q, n) { \
        float dot = faddrn(faddrn(fmulrn(sz, (q).z), fmulrn(sy, (q).y)), fmulrn(sx, (q).x)); \
        float d = fsubrn(faddrn(s2, (q).w), fmulrn(2.0f, dot)); \
        uint32_t bits = __float_as_uint(d); \
        uint32_t key  = bits ^ (((uint32_t)((int32_t)bits >> 31)) | 0x80000000u); \
        unsigned long long c = ((unsigned long long)key << 32) | (uint32_t)(n); \
        if (c < v15){ \
            INS(0) INS(1) INS(2) INS(3) INS(4) INS(5) INS(6) INS(7) \
            INS(8) INS(9) INS(10) INS(11) INS(12) INS(13) INS(14) INS(15) \
        } }
#define INS(t) { bool lt = c < v##t; \
                 unsigned long long lo = lt ? c : v##t; \
                 unsigned long long hi = lt ? v##t : c; \
                 v##t = lo; c = hi; }

    #pragma unroll 1
    for (int j = 0; j < N_/64; j += 4){
        const int n0 = (j << 6) | lane;
        float4 q0 = P[n0];
        float4 q1 = P[n0 + 64];
        float4 q2 = P[n0 + 128];
        float4 q3 = P[n0 + 192];
        PROC(q0, n0)
        PROC(q1, n0 + 64)
        PROC(q2, n0 + 128)
        PROC(q3, n0 + 192)
    }
#undef INS
#undef PROC

    // merge: 16 rounds of wave-min over per-lane heads; winner lane consumes.
    uint32_t myidx = 0;
    const int myr = lane >> 2;
    #pragma unroll 1
    for (int r = 0; r < KNN_; ++r){
        unsigned long long h = v0;
        unsigned long long g = h;
        #pragma unroll
        for (int off = 1; off < 64; off <<= 1){
            unsigned long long o = __shfl_xor(g, off, 64);
            if (o < g) g = o;
        }
        if (h == g){                          // unique winner (idx is unique)
            v0=v1; v1=v2; v2=v3; v3=v4; v4=v5; v5=v6; v6=v7; v7=v8;
            v8=v9; v9=v10; v10=v11; v11=v12; v12=v13; v13=v14; v14=v15;
            v15=~0ULL;
        }
        if (myr == r) myidx = (uint32_t)g;    // keep idx of my output row
    }

    // gather + write: lane l handles neighbor r=l>>2, channels 4*(l&3)..+3
    const int c4 = lane & 3;
    const float4* X4 = (const float4*)x;
    float4 valq = X4[((size_t)b * N_ + myidx) * 4 + c4];
    float4* O4 = (float4*)out;
    O4[(((size_t)b * NPOINT + p) * KNN_ + myr) * 4 + c4] = valq;
}

// ---------------------------------------------------------------------------
extern "C" void kernel_launch(void* const* d_in, const int* in_sizes, int n_in,
                              void* d_out, int out_size, void* d_ws, size_t ws_size,
                              hipStream_t stream) {
    const float* x = (const float*)d_in[0];
    float* out = (float*)d_out;

    // workspace layout: [B_*N_ float4 packed points][B_*NPOINT float4 samples]
    const size_t pts_bytes = (size_t)B_ * N_ * sizeof(float4);
    const size_t s_bytes   = (size_t)B_ * NPOINT * sizeof(float4);
    if (ws_size < pts_bytes + s_bytes) return;   // visible failure if ws too small
    float4* pts   = (float4*)d_ws;
    float4* s_arr = (float4*)((char*)d_ws + pts_bytes);

    prep_kernel<<<(B_*N_ + 255)/256, 256, 0, stream>>>(x, pts);
    fps_kernel<<<B_, FPS_T, FPS_LDS_BYTES, stream>>>(pts, s_arr);
    knn_kernel<<<(B_*NPOINT)/4, 256, 0, stream>>>(x, pts, s_arr, out);
}

// Round 13
// 1055.706 us; speedup vs baseline: 1.2491x; 1.0570x over previous
//
#include <hip/hip_runtime.h>
#include <hip/hip_bf16.h>
#include <stdint.h>

// Problem constants (from reference)
#define B_      8
#define N_      16384
#define NPOINT  512
#define KNN_    16
#define C_      16

// Exact IEEE f32 ops — bit-match the numpy (ref=np) lowering:
//   p2/s2 : np.sum(v*v,-1)  -> pairwise small-n ASCENDING:  (x2+y2)+z2, no FMA
//   FPS d : np.sum(dd*dd,-1)-> ASCENDING:  (dx2+dy2)+dz2, no FMA
//   dot   : np.einsum unopt -> sum_of_products_contig_two remainder switch,
//           DESCENDING fallthrough:  ((sz*pz) + sy*py) + sx*px, no FMA
//   dist  : (s2 + p2) - 2*dot   elementwise, no FMA
__device__ __forceinline__ float fmulrn(float a, float b){ return __fmul_rn(a,b); }
__device__ __forceinline__ float faddrn(float a, float b){ return __fadd_rn(a,b); }
__device__ __forceinline__ float fsubrn(float a, float b){ return __fsub_rn(a,b); }

// ---------------------------------------------------------------------------
// DPP reductions (VALU pipe, zero LDS ops).
// ---------------------------------------------------------------------------
__device__ __forceinline__ uint32_t umax_(uint32_t a, uint32_t b){ return a > b ? a : b; }

// 4-step row_shr reduce: lane 15 of each 16-lane row = max of that row.
__device__ __forceinline__ uint32_t row16_max(uint32_t x){
    uint32_t t;
    t = (uint32_t)__builtin_amdgcn_update_dpp((int)x, (int)x, 0x111, 0xf, 0xf, false); x = umax_(x, t);
    t = (uint32_t)__builtin_amdgcn_update_dpp((int)x, (int)x, 0x112, 0xf, 0xf, false); x = umax_(x, t);
    t = (uint32_t)__builtin_amdgcn_update_dpp((int)x, (int)x, 0x114, 0xf, 0xf, false); x = umax_(x, t);
    t = (uint32_t)__builtin_amdgcn_update_dpp((int)x, (int)x, 0x118, 0xf, 0xf, false); x = umax_(x, t);
    return x;
}

// Full 64-lane max as a UNIFORM value: row reduce + 4 readlane + scalar max.
__device__ __forceinline__ uint32_t wave_max_uniform(uint32_t x){
    x = row16_max(x);
    uint32_t a = (uint32_t)__builtin_amdgcn_readlane((int)x, 15);
    uint32_t b = (uint32_t)__builtin_amdgcn_readlane((int)x, 31);
    uint32_t c = (uint32_t)__builtin_amdgcn_readlane((int)x, 47);
    uint32_t d = (uint32_t)__builtin_amdgcn_readlane((int)x, 63);
    return umax_(umax_(a, b), umax_(c, d));
}

// u64 max across each quad (lanes 4k..4k+3) via 2 quad_perm DPP steps.
// After this, every lane holds the max of its quad's 4 values.
__device__ __forceinline__ unsigned long long quad_max_u64(unsigned long long k){
    uint32_t lo = (uint32_t)k, hi = (uint32_t)(k >> 32);
    {   // quad_perm [1,0,3,2] = 0xB1
        uint32_t olo = (uint32_t)__builtin_amdgcn_update_dpp((int)lo, (int)lo, 0xB1, 0xf, 0xf, false);
        uint32_t ohi = (uint32_t)__builtin_amdgcn_update_dpp((int)hi, (int)hi, 0xB1, 0xf, 0xf, false);
        bool take = (ohi > hi) || (ohi == hi && olo > lo);
        hi = take ? ohi : hi; lo = take ? olo : lo;
    }
    {   // quad_perm [2,3,0,1] = 0x4E
        uint32_t olo = (uint32_t)__builtin_amdgcn_update_dpp((int)lo, (int)lo, 0x4E, 0xf, 0xf, false);
        uint32_t ohi = (uint32_t)__builtin_amdgcn_update_dpp((int)hi, (int)hi, 0x4E, 0xf, 0xf, false);
        bool take = (ohi > hi) || (ohi == hi && olo > lo);
        hi = take ? ohi : hi; lo = take ? olo : lo;
    }
    return ((unsigned long long)hi << 32) | lo;
}

// ---------------------------------------------------------------------------
// Kernel 1: pack {x, y, z, p2} per point.  p2 = (x*x + y*y) + z*z  (ascending).
// ---------------------------------------------------------------------------
__global__ void prep_kernel(const float* __restrict__ x, float4* __restrict__ pts){
    int i = blockIdx.x * blockDim.x + threadIdx.x;   // 0 .. B_*N_-1
    if (i >= B_ * N_) return;
    const float4* x4 = (const float4*)x;             // x row = 16 floats = 4 float4
    float4 q = x4[(size_t)i * 4];                    // channels 0..3: x,y,z,c3
    float p2 = faddrn(faddrn(fmulrn(q.x,q.x), fmulrn(q.y,q.y)), fmulrn(q.z,q.z));
    pts[i] = make_float4(q.x, q.y, q.z, p2);
}

// ---------------------------------------------------------------------------
// Kernel 1b: zero the cross-block mailbox region (MUST run every launch —
// graph replays reuse ws and stale keys would satisfy the spin early).
// ---------------------------------------------------------------------------
#define FPS_NB  4          // blocks per batch
__global__ void zero_part_kernel(unsigned long long* __restrict__ part){
    int i = blockIdx.x * blockDim.x + threadIdx.x;
    if (i < B_ * NPOINT * FPS_NB) part[i] = 0ULL;
}

// ---------------------------------------------------------------------------
// Kernel 2: multi-block FPS — FPS_NB blocks per batch, winner exchange via
// agent-scope atomics on an L2 mailbox. R12 post-mortem: single block/batch
// is VALU-saturated on 8 of 256 CUs (per-active-CU VALUBusy ~99%, 4000
// cyc/iter). Split: each block owns N_/FPS_NB points (4 slots), publishes a
// u64 key {hi = f32 bits of block-max min_d, lo = ~global_idx}; max over
// keys == (max val, min idx) == numpy first-occurrence argmax, bit-exact.
// Key is never 0 (lo = ~idx, idx < 2^17) -> nonzero IS the ready flag; the
// mailbox is re-zeroed by zero_part_kernel each launch. Bounded spin bails
// out (visible failure, no hang). blockIdx mapping b=idx&7, blk=idx>>3 puts
// a batch's blocks on one XCD (round-robin heuristic; correctness-neutral).
// ---------------------------------------------------------------------------
#define FPS_T    1024
#define FPS_NW   (FPS_T/64)          // 16 waves
#define SLICE    (N_ / FPS_NB)       // 4096 points per block
#define SLOTS_MB (SLICE / FPS_T)     // 4 slots per thread

#define FOR_S4(F) F(0) F(1) F(2) F(3)

__global__ void __launch_bounds__(FPS_T)
fps_kernel_mb(const float4* __restrict__ pts, float4* __restrict__ s_out,
              unsigned long long* __restrict__ part){
    __shared__ float2   xy[SLICE];              // 32 KiB slice of (x,y)
    __shared__ uint32_t red_v[2][FPS_NW];
    __shared__ uint32_t red_i[2][FPS_NW];

    const int b    = blockIdx.x & 7;            // batch  (same XCD per batch)
    const int blk  = blockIdx.x >> 3;           // sub-block 0..FPS_NB-1
    const int tid  = threadIdx.x;
    const int lane = tid & 63;
    const int wv   = tid >> 6;
    const int base = blk * SLICE;               // global offset of this slice
    const float4* P = pts + (size_t)b * N_;
    unsigned long long* mbox = part + ((size_t)b * NPOINT) * FPS_NB;

#define DECL_S(s) float z##s, md##s;
    FOR_S4(DECL_S)
#undef DECL_S

#define INIT_S(s) { float4 q = P[base + (s) * FPS_T + tid]; \
        xy[(s) * FPS_T + tid] = make_float2(q.x, q.y); \
        z##s = q.z; md##s = 1e10f; }
    FOR_S4(INIT_S)
#undef INIT_S

    float lx, ly, lz;
    {
        float4 q0 = P[0];                       // seed = index 0
        lx = q0.x; ly = q0.y; lz = q0.z;
        if (blk == 0 && tid == 0) s_out[(size_t)b * NPOINT + 0] = q0;
    }
    __syncthreads();                            // staging visible

    for (int it = 1; it < NPOINT; ++it){
        float    bv = -1.0f;                    // all min_d >= 0
        uint32_t bi = 0;                        // GLOBAL point index
        // slots ascend in global index -> strict > keeps first occurrence
#define DO_S(s) { \
        float2 c = xy[(s) * FPS_T + tid]; \
        float dx = fsubrn(c.x, lx); \
        float dy = fsubrn(c.y, ly); \
        float dz = fsubrn(z##s, lz); \
        float d  = faddrn(faddrn(fmulrn(dx,dx), fmulrn(dy,dy)), fmulrn(dz,dz)); \
        md##s = fminf(md##s, d); \
        if (md##s > bv){ bv = md##s; bi = (uint32_t)(base + (s) * FPS_T + tid); } }
        FOR_S4(DO_S)
#undef DO_S

        // ---- in-block reduce (DPP, uniform) ----
        uint32_t vb    = __float_as_uint(bv);
        uint32_t gmaxw = wave_max_uniform(vb);
        uint32_t gidxw = wave_max_uniform((vb == gmaxw) ? ~bi : 0u);
        const int par = it & 1;
        if (lane == 0){ red_v[par][wv] = gmaxw; red_i[par][wv] = gidxw; }
        __syncthreads();
        uint32_t rv = red_v[par][lane & 15];
        uint32_t ri = red_i[par][lane & 15];
        uint32_t gv = (uint32_t)__builtin_amdgcn_readlane((int)row16_max(rv), 15);
        uint32_t gn = (uint32_t)__builtin_amdgcn_readlane(
                          (int)row16_max((rv == gv) ? ri : 0u), 15);
        unsigned long long kblk = ((unsigned long long)gv << 32) | gn; // never 0

        // ---- publish + poll mailbox (agent scope, L1-bypassing) ----
        unsigned long long* slotp = mbox + (size_t)it * FPS_NB;
        if (tid == 0)
            __hip_atomic_store(&slotp[blk], kblk, __ATOMIC_RELAXED,
                               __HIP_MEMORY_SCOPE_AGENT);
        unsigned long long v = 0;
        int guard = 0;
        for (;;){
            if (v == 0)
                v = __hip_atomic_load(&slotp[lane & 3], __ATOMIC_RELAXED,
                                      __HIP_MEMORY_SCOPE_AGENT);
            if (__all(v != 0ULL)) break;
            if (++guard > (1 << 20)) return;    // bail: fail fast, never hang
        }
        unsigned long long kmax = quad_max_u64(v);   // global winner, all lanes
        uint32_t gi  = ~((uint32_t)kmax);
        uint32_t giu = (uint32_t)__builtin_amdgcn_readfirstlane((int)gi);
        float4 q = P[giu];                       // uniform -> scalar load path
        lx = q.x; ly = q.y; lz = q.z;
        if (blk == 0 && tid == 0) s_out[(size_t)b * NPOINT + it] = q;
    }
}

// ---------------------------------------------------------------------------
// Kernel 3: exact 16-NN per sample row — UNCHANGED from R11/R12 (isolate fps
// delta). Redesign (u32-key threshold select) queued next round.
// ---------------------------------------------------------------------------
#define FOR_V(F) F(0) F(1) F(2) F(3) F(4) F(5) F(6) F(7) \
                 F(8) F(9) F(10) F(11) F(12) F(13) F(14) F(15)

__global__ void __launch_bounds__(256)
__attribute__((amdgpu_waves_per_eu(4, 4)))
knn_kernel(const float* __restrict__ x,
           const float4* __restrict__ pts,
           const float4* __restrict__ s_arr,
           float* __restrict__ out){
    const int wv   = threadIdx.x >> 6;
    const int lane = threadIdx.x & 63;
    const int blk  = blockIdx.x;            // 0 .. B_*NPOINT/4 - 1
    const int b    = blk >> 7;              // 128 blocks per batch
    const int p    = ((blk & 127) << 2) | wv;

    const float4 s = s_arr[(size_t)b * NPOINT + p];
    const float sx = s.x, sy = s.y, sz = s.z, s2 = s.w;
    const float4* P = pts + (size_t)b * N_;

#define DECLV(t) unsigned long long v##t = ~0ULL;
    FOR_V(DECLV)
#undef DECLV

#define PROC(q, n) { \
        float dot = faddrn(faddrn(fmulrn(sz, (q).z), fmulrn(sy, (q).y)), fmulrn(sx, (q).x)); \
        float d = fsubrn(faddrn(s2, (q).w), fmulrn(2.0f, dot)); \
        uint32_t bits = __float_as_uint(d); \
        uint32_t key  = bits ^ (((uint32_t)((int32_t)bits >> 31)) | 0x80000000u); \
        unsigned long long c = ((unsigned long long)key << 32) | (uint32_t)(n); \
        if (c < v15){ \
            INS(0) INS(1) INS(2) INS(3) INS(4) INS(5) INS(6) INS(7) \
            INS(8) INS(9) INS(10) INS(11) INS(12) INS(13) INS(14) INS(15) \
        } }
#define INS(t) { bool lt = c < v##t; \
                 unsigned long long lo = lt ? c : v##t; \
                 unsigned long long hi = lt ? v##t : c; \
                 v##t = lo; c = hi; }

    #pragma unroll 1
    for (int j = 0; j < N_/64; j += 4){
        const int n0 = (j << 6) | lane;
        float4 q0 = P[n0];
        float4 q1 = P[n0 + 64];
        float4 q2 = P[n0 + 128];
        float4 q3 = P[n0 + 192];
        PROC(q0, n0)
        PROC(q1, n0 + 64)
        PROC(q2, n0 + 128)
        PROC(q3, n0 + 192)
    }
#undef INS
#undef PROC

    // merge: 16 rounds of wave-min over per-lane heads; winner lane consumes.
    uint32_t myidx = 0;
    const int myr = lane >> 2;
    #pragma unroll 1
    for (int r = 0; r < KNN_; ++r){
        unsigned long long h = v0;
        unsigned long long g = h;
        #pragma unroll
        for (int off = 1; off < 64; off <<= 1){
            unsigned long long o = __shfl_xor(g, off, 64);
            if (o < g) g = o;
        }
        if (h == g){                          // unique winner (idx is unique)
            v0=v1; v1=v2; v2=v3; v3=v4; v4=v5; v5=v6; v6=v7; v7=v8;
            v8=v9; v9=v10; v10=v11; v11=v12; v12=v13; v13=v14; v14=v15;
            v15=~0ULL;
        }
        if (myr == r) myidx = (uint32_t)g;    // keep idx of my output row
    }

    // gather + write: lane l handles neighbor r=l>>2, channels 4*(l&3)..+3
    const int c4 = lane & 3;
    const float4* X4 = (const float4*)x;
    float4 valq = X4[((size_t)b * N_ + myidx) * 4 + c4];
    float4* O4 = (float4*)out;
    O4[(((size_t)b * NPOINT + p) * KNN_ + myr) * 4 + c4] = valq;
}

// ---------------------------------------------------------------------------
extern "C" void kernel_launch(void* const* d_in, const int* in_sizes, int n_in,
                              void* d_out, int out_size, void* d_ws, size_t ws_size,
                              hipStream_t stream) {
    const float* x = (const float*)d_in[0];
    float* out = (float*)d_out;

    // workspace: [pts: B_*N_ float4][s_arr: B_*NPOINT float4][mailbox u64s]
    const size_t pts_bytes  = (size_t)B_ * N_ * sizeof(float4);
    const size_t s_bytes    = (size_t)B_ * NPOINT * sizeof(float4);
    const size_t part_bytes = (size_t)B_ * NPOINT * FPS_NB * sizeof(unsigned long long);
    if (ws_size < pts_bytes + s_bytes + part_bytes) return;
    float4* pts   = (float4*)d_ws;
    float4* s_arr = (float4*)((char*)d_ws + pts_bytes);
    unsigned long long* part =
        (unsigned long long*)((char*)d_ws + pts_bytes + s_bytes);

    prep_kernel<<<(B_*N_ + 255)/256, 256, 0, stream>>>(x, pts);
    zero_part_kernel<<<(B_*NPOINT*FPS_NB + 255)/256, 256, 0, stream>>>(part);
    fps_kernel_mb<<<B_*FPS_NB, FPS_T, 0, stream>>>(pts, s_arr, part);
    knn_kernel<<<(B_*NPOINT)/4, 256, 0, stream>>>(x, pts, s_arr, out);
}